// Round 13
// baseline (243.235 us; speedup 1.0000x reference)
//
#include <hip/hip_runtime.h>
#include <hip/hip_bf16.h>
#include <hip/hip_fp8.h>

#define MROWS 8192   // N*T
#define KDIM  512    // CIN
#define NCOL  8192   // codebook size K
#define TSEQ  2048

typedef float f32x4 __attribute__((ext_vector_type(4)));

__device__ __forceinline__ unsigned int pack4_fp8(float a, float b, float c, float d) {
#if __has_builtin(__builtin_amdgcn_cvt_pk_fp8_f32)
  int r = __builtin_amdgcn_cvt_pk_fp8_f32(a, b, 0, false);
  r = __builtin_amdgcn_cvt_pk_fp8_f32(c, d, r, true);
  return (unsigned int)r;
#else
  __hip_fp8_e4m3 ha(a), hb(b), hc(c), hd(d);
  return (unsigned int)ha.__x | ((unsigned int)hb.__x << 8) |
         ((unsigned int)hc.__x << 16) | ((unsigned int)hd.__x << 24);
#endif
}

// exact OCP e4m3 decode
__device__ __forceinline__ float fp8d(unsigned char b) {
  unsigned int s = b >> 7, e = (b >> 3) & 15, m = b & 7;
  if (e == 0) {
    float v = (float)m * 0.001953125f;
    return s ? -v : v;
  }
  unsigned int bits = (s << 31) | ((e + 120) << 23) | (m << 20);
  return __uint_as_float(bits);
}

// ---------------- prep: convA, convB-transpose, fproj (no normalize), init ----------------
// [0,4096): convA   [4096,5120): convB   [5120,5632): fproj   [5632,5664): init amin/rowsum/out
__global__ void prep_kernel(const float* __restrict__ X, unsigned char* __restrict__ A8,
                            const float* __restrict__ W, unsigned char* __restrict__ B8,
                            const float* __restrict__ feats, const float* __restrict__ proj,
                            float* __restrict__ F, unsigned long long* __restrict__ amin,
                            float* __restrict__ rowsum, float* __restrict__ out) {
  __shared__ float tile[64][65];
  const int tid = threadIdx.x;
  int b = blockIdx.x;
  if (b < 4096) {
    int i = b * 256 + tid;                 // float4 index
    float4 v = reinterpret_cast<const float4*>(X)[i];
    reinterpret_cast<unsigned int*>(A8)[i] = pack4_fp8(v.x, v.y, v.z, v.w);
  } else if (b < 5120) {
    b -= 4096;
    const int bx = b & 127, by = b >> 7;    // 128 col-tiles x 8 row-tiles of W
    const int c4 = tid & 15, rr = tid >> 4;
    #pragma unroll
    for (int p = 0; p < 4; ++p) {
      int row = p * 16 + rr;
      float4 v = reinterpret_cast<const float4*>(W + (size_t)(by * 64 + row) * NCOL + bx * 64)[c4];
      tile[row][c4 * 4 + 0] = v.x; tile[row][c4 * 4 + 1] = v.y;
      tile[row][c4 * 4 + 2] = v.z; tile[row][c4 * 4 + 3] = v.w;
    }
    __syncthreads();
    #pragma unroll
    for (int p = 0; p < 4; ++p) {
      int oc = p * 16 + rr;               // output row (W col)
      unsigned int pk = pack4_fp8(tile[c4 * 4 + 0][oc], tile[c4 * 4 + 1][oc],
                                  tile[c4 * 4 + 2][oc], tile[c4 * 4 + 3][oc]);
      *reinterpret_cast<unsigned int*>(B8 + (size_t)(bx * 64 + oc) * KDIM + by * 64 + c4 * 4) = pk;
    }
  } else if (b < 5632) {
    b -= 5120;
    int rl = tid >> 4, d = tid & 15;
    int row = b * 16 + rl;
    const float4* fr4 = reinterpret_cast<const float4*>(feats + (size_t)row * KDIM);
    float acc = 0.f;
    #pragma unroll 4
    for (int kc = 0; kc < KDIM / 4; ++kc) {
      float4 v = fr4[kc];
      const float* p = proj + (size_t)kc * 64 + d;
      acc += v.x * p[0] + v.y * p[16] + v.z * p[32] + v.w * p[48];
    }
    F[(size_t)row * 16 + d] = acc;        // unnormalized: argmax dot == ref argmin
  } else {
    int r = (b - 5632) * 256 + tid;
    amin[r] = ~0ull;
    rowsum[r] = 0.f;
    if (b == 5632 && tid == 0) out[0] = 0.f;
  }
}

// ---------------- fused: codebook-argmax (first 512 blocks) + GEMM (fp8, 3-deep pipeline) ----------------
#define TGT_BLOCKS 512
#define CB_CODES 128

__device__ __forceinline__ void gld16(const void* g, void* l3) {
  __builtin_amdgcn_global_load_lds((const __attribute__((address_space(1))) void*)g,
                                   (__attribute__((address_space(3))) void*)l3, 16, 0, 0);
}

__global__ __launch_bounds__(256, 4)
void gemm_targets_kernel(const unsigned char* __restrict__ A,  // [MROWS][KDIM] fp8
                         const unsigned char* __restrict__ B,  // [NCOL][KDIM] fp8 (W^T)
                         const float* __restrict__ bias,
                         float* __restrict__ rowsum,
                         const float* __restrict__ F,
                         const float* __restrict__ cb,
                         unsigned long long* __restrict__ amin) {
  __shared__ __align__(16) unsigned char smem[49152];
  const int tid = threadIdx.x;
  const int bid = blockIdx.x;

  if (bid < TGT_BLOCKS) {
    // ---- targets path: block owns 1024 rows x 128 codes; u64 atomicMin merge ----
    float (*csh)[16] = (float (*)[16])smem;
    const int r0 = (bid & 7) * 1024 + tid;
    const int c0 = (bid >> 3) * CB_CODES;
    {
      int ci = tid >> 1, half = tid & 1;
      const float4* src = reinterpret_cast<const float4*>(cb + (size_t)(c0 + ci) * 16 + half * 8);
      float4 v0 = src[0], v1 = src[1];
      float4* dst = reinterpret_cast<float4*>(&csh[ci][half * 8]);
      dst[0] = v0; dst[1] = v1;
    }
    float4 fa[4][4];
    #pragma unroll
    for (int q = 0; q < 4; ++q) {
      const float4* fp = reinterpret_cast<const float4*>(F + (size_t)(r0 + q * 256) * 16);
      fa[q][0] = fp[0]; fa[q][1] = fp[1]; fa[q][2] = fp[2]; fa[q][3] = fp[3];
    }
    __syncthreads();

    float best[4] = {3.4e38f, 3.4e38f, 3.4e38f, 3.4e38f};
    int bidx[4] = {0, 0, 0, 0};
    #pragma unroll 2
    for (int ci = 0; ci < CB_CODES; ++ci) {
      const float4* cvp = reinterpret_cast<const float4*>(&csh[ci][0]);
      float4 c0v = cvp[0], c1v = cvp[1], c2v = cvp[2], c3v = cvp[3];
      #pragma unroll
      for (int q = 0; q < 4; ++q) {
        float dot = fa[q][0].x*c0v.x + fa[q][0].y*c0v.y + fa[q][0].z*c0v.z + fa[q][0].w*c0v.w
                  + fa[q][1].x*c1v.x + fa[q][1].y*c1v.y + fa[q][1].z*c1v.z + fa[q][1].w*c1v.w
                  + fa[q][2].x*c2v.x + fa[q][2].y*c2v.y + fa[q][2].z*c2v.z + fa[q][2].w*c2v.w
                  + fa[q][3].x*c3v.x + fa[q][3].y*c3v.y + fa[q][3].z*c3v.z + fa[q][3].w*c3v.w;
        float d = -dot;
        if (d < best[q]) { best[q] = d; bidx[q] = c0 + ci; }
      }
    }
    #pragma unroll
    for (int q = 0; q < 4; ++q) {
      unsigned int u = __float_as_uint(best[q]);
      unsigned int key = (u & 0x80000000u) ? ~u : (u | 0x80000000u);  // order-preserving
      unsigned long long pk = ((unsigned long long)key << 32) | (unsigned int)bidx[q];
      atomicMin(&amin[r0 + q * 256], pk);
    }
    return;
  }

  // ---- gemm path: 128x128 tile, BK=64, 3-deep LDS pipeline with counted vmcnt ----
  const int gid = bid - TGT_BLOCKS;
  const int wave = tid >> 6;
  const int lane = tid & 63;
  const int xcd = gid & 7, idx = gid >> 3;
  const int bx = xcd * 8 + (idx & 7);
  const int by = idx >> 3;
  const int row0 = by * 128;
  const int col0 = bx * 128;
  const int wr = wave >> 1, wc = wave & 1;
  unsigned char* As = smem;            // [3 bufs][128 rows][64B]
  unsigned char* Bs = smem + 24576;

  f32x4 acc[4][4];
  #pragma unroll
  for (int i = 0; i < 4; ++i)
    #pragma unroll
    for (int j = 0; j < 4; ++j) acc[i][j] = (f32x4){0.f, 0.f, 0.f, 0.f};

  const int lr = lane >> 2;                               // 16 rows per gld16
  const int lcs = (((lane & 3) ^ ((lane >> 3) & 3)) << 4);// pre-swizzled src 16B slot

  const int l15 = lane & 15, l16 = lane >> 4;
  const int sw = (l15 >> 1) & 3;
  const int subo = (l16 & 1) * 8;
  const int lg16 = l16 >> 1;

  // prologue: stage tiles 0,1 into bufs 0,1 (8 loads/wave in flight)
  #pragma unroll
  for (int t0 = 0; t0 < 2; ++t0) {
    const int kt = t0 * 64, buf = t0 * 8192;
    #pragma unroll
    for (int c = 0; c < 2; ++c) {
      int rchunk = (wave * 2 + c) * 16;
      gld16(A + (size_t)(row0 + rchunk + lr) * KDIM + kt + lcs, As + buf + rchunk * 64);
      gld16(B + (size_t)(col0 + rchunk + lr) * KDIM + kt + lcs, Bs + buf + rchunk * 64);
    }
  }
  asm volatile("s_waitcnt vmcnt(4)" ::: "memory");   // tile0 landed; tile1 in flight
  __builtin_amdgcn_s_barrier();

  #pragma unroll
  for (int t = 0; t < 8; ++t) {
    const int cur = (t % 3) * 8192;
    // issue prefetch for t+2 (one full K-step of latency slack)
    if (t + 2 < 8) {
      const int kt = (t + 2) * 64;
      const int nxt = ((t + 2) % 3) * 8192;
      #pragma unroll
      for (int c = 0; c < 2; ++c) {
        int rchunk = (wave * 2 + c) * 16;
        gld16(A + (size_t)(row0 + rchunk + lr) * KDIM + kt + lcs, As + nxt + rchunk * 64);
        gld16(B + (size_t)(col0 + rchunk + lr) * KDIM + kt + lcs, Bs + nxt + rchunk * 64);
      }
    }
    // compute current buffer
    #pragma unroll
    for (int ks = 0; ks < 2; ++ks) {
      const int poff = (((ks * 2 + lg16) ^ sw) << 4) + subo;
      long af[4], bb[4];
      #pragma unroll
      for (int mi = 0; mi < 4; ++mi)
        af[mi] = *(const long*)(As + cur + (wr * 64 + mi * 16 + l15) * 64 + poff);
      #pragma unroll
      for (int ni = 0; ni < 4; ++ni)
        bb[ni] = *(const long*)(Bs + cur + (wc * 64 + ni * 16 + l15) * 64 + poff);
      #pragma unroll
      for (int mi = 0; mi < 4; ++mi)
        #pragma unroll
        for (int ni = 0; ni < 4; ++ni)
          acc[mi][ni] = __builtin_amdgcn_mfma_f32_16x16x32_fp8_fp8(af[mi], bb[ni], acc[mi][ni], 0, 0, 0);
    }
    // wait only for the NEXT tile's loads (issued last iteration), not the new ones
    if (t < 6) {
      asm volatile("s_waitcnt vmcnt(4)" ::: "memory");
      __builtin_amdgcn_s_barrier();
    } else if (t == 6) {
      asm volatile("s_waitcnt vmcnt(0)" ::: "memory");
      __builtin_amdgcn_s_barrier();
    }
  }

  // slim epilogue: per-row partial sum(exp(logit))
  float bv[4];
  #pragma unroll
  for (int ni = 0; ni < 4; ++ni)
    bv[ni] = bias[col0 + wc * 64 + ni * 16 + l15];
  #pragma unroll
  for (int mi = 0; mi < 4; ++mi) {
    int rbase = row0 + wr * 64 + mi * 16 + l16 * 4;
    #pragma unroll
    for (int j = 0; j < 4; ++j) {
      float se = 0.f;
      #pragma unroll
      for (int ni = 0; ni < 4; ++ni)
        se += __expf(acc[mi][ni][j] + bv[ni]);
      #pragma unroll
      for (int o = 1; o < 16; o <<= 1) se += __shfl_xor(se, o);
      if (l15 == 0) atomicAdd(&rowsum[rbase + j], se);
    }
  }
}

// ---------------- merged: target logit + masked-mean loss ----------------
// 64 blocks x 256; each wave handles 32 rows; atomicAdd pre-scaled nll.
__global__ void tgtloss_kernel(const unsigned char* __restrict__ A,
                               const unsigned char* __restrict__ B,
                               const float* __restrict__ bias,
                               const unsigned long long* __restrict__ amin,
                               const float* __restrict__ rowsum,
                               const int* __restrict__ lens,
                               float* __restrict__ out) {
  __shared__ float sp[4];
  const int wave = threadIdx.x >> 6, lane = threadIdx.x & 63;
  const int cnt = lens[0] + lens[1] + lens[2] + lens[3];
  const float inv = 1.0f / (float)max(cnt, 1);
  float partial = 0.f;
  #pragma unroll 4
  for (int i = 0; i < 32; ++i) {
    const int r = blockIdx.x * 128 + wave * 32 + i;
    const int tg = (int)(amin[r] & 0xffffffffull);
    uint2 ua = reinterpret_cast<const uint2*>(A + (size_t)r * KDIM)[lane];
    uint2 ub = reinterpret_cast<const uint2*>(B + (size_t)tg * KDIM)[lane];
    float s = 0.f;
    const unsigned char* pa = reinterpret_cast<const unsigned char*>(&ua);
    const unsigned char* pb = reinterpret_cast<const unsigned char*>(&ub);
    #pragma unroll
    for (int k = 0; k < 8; ++k) s += fp8d(pa[k]) * fp8d(pb[k]);
    #pragma unroll
    for (int o = 1; o < 64; o <<= 1) s += __shfl_xor(s, o);
    const int n = r >> 11, t = r & (TSEQ - 1);
    if (lane == 0 && t < lens[n])
      partial += logf(rowsum[r]) - (s + bias[tg]);
  }
  if (lane == 0) sp[wave] = partial;
  __syncthreads();
  if (threadIdx.x == 0)
    atomicAdd(out, (sp[0] + sp[1] + sp[2] + sp[3]) * inv);
}

extern "C" void kernel_launch(void* const* d_in, const int* in_sizes, int n_in,
                              void* d_out, int out_size, void* d_ws, size_t ws_size,
                              hipStream_t stream) {
  const float* feats    = (const float*)d_in[0];
  const float* context  = (const float*)d_in[1];
  const int*   lens     = (const int*)d_in[2];
  const float* proj     = (const float*)d_in[3];
  const float* codebook = (const float*)d_in[4];
  const float* W_enc    = (const float*)d_in[5];
  const float* b_enc    = (const float*)d_in[6];
  float* out = (float*)d_out;

  char* ws = (char*)d_ws;
  unsigned char* A8 = (unsigned char*)(ws);                       // 4 MB
  unsigned char* B8 = (unsigned char*)(ws + 4194304);             // 4 MB
  float* F          = (float*)(ws + 8388608);                     // 512 KB
  unsigned long long* amin = (unsigned long long*)(ws + 8912896); // 64 KB
  float* rowsum     = (float*)(ws + 8978432);                     // 32 KB

  // 1) conversions + projection + init (also zeroes out[0])
  prep_kernel<<<5664, 256, 0, stream>>>(context, A8, W_enc, B8, feats, proj, F, amin, rowsum, out);
  // 2) codebook argmax (first 512 blocks)  ||  GEMM(3-deep)+rowsum(exp)
  gemm_targets_kernel<<<TGT_BLOCKS + 4096, 256, 0, stream>>>(A8, B8, b_enc, rowsum, F, codebook, amin);
  // 3) target logit + masked-mean loss
  tgtloss_kernel<<<64, 256, 0, stream>>>(A8, B8, b_enc, amin, rowsum, lens, out);
}

// Round 14
// 212.510 us; speedup vs baseline: 1.1446x; 1.1446x over previous
//
#include <hip/hip_runtime.h>
#include <hip/hip_bf16.h>
#include <hip/hip_fp8.h>

#define MROWS 8192   // N*T
#define KDIM  512    // CIN
#define NCOL  8192   // codebook size K
#define TSEQ  2048

typedef float f32x4 __attribute__((ext_vector_type(4)));

__device__ __forceinline__ unsigned int pack4_fp8(float a, float b, float c, float d) {
#if __has_builtin(__builtin_amdgcn_cvt_pk_fp8_f32)
  int r = __builtin_amdgcn_cvt_pk_fp8_f32(a, b, 0, false);
  r = __builtin_amdgcn_cvt_pk_fp8_f32(c, d, r, true);
  return (unsigned int)r;
#else
  __hip_fp8_e4m3 ha(a), hb(b), hc(c), hd(d);
  return (unsigned int)ha.__x | ((unsigned int)hb.__x << 8) |
         ((unsigned int)hc.__x << 16) | ((unsigned int)hd.__x << 24);
#endif
}

// exact OCP e4m3 decode
__device__ __forceinline__ float fp8d(unsigned char b) {
  unsigned int s = b >> 7, e = (b >> 3) & 15, m = b & 7;
  if (e == 0) {
    float v = (float)m * 0.001953125f;
    return s ? -v : v;
  }
  unsigned int bits = (s << 31) | ((e + 120) << 23) | (m << 20);
  return __uint_as_float(bits);
}

// ---------------- prep: convA, convB-transpose, fproj (no normalize), init ----------------
// [0,4096): convA   [4096,5120): convB   [5120,5632): fproj   [5632,5664): init amin/rowsum/out
__global__ void prep_kernel(const float* __restrict__ X, unsigned char* __restrict__ A8,
                            const float* __restrict__ W, unsigned char* __restrict__ B8,
                            const float* __restrict__ feats, const float* __restrict__ proj,
                            float* __restrict__ F, unsigned long long* __restrict__ amin,
                            float* __restrict__ rowsum, float* __restrict__ out) {
  __shared__ float tile[64][65];
  const int tid = threadIdx.x;
  int b = blockIdx.x;
  if (b < 4096) {
    int i = b * 256 + tid;                 // float4 index
    float4 v = reinterpret_cast<const float4*>(X)[i];
    reinterpret_cast<unsigned int*>(A8)[i] = pack4_fp8(v.x, v.y, v.z, v.w);
  } else if (b < 5120) {
    b -= 4096;
    const int bx = b & 127, by = b >> 7;    // 128 col-tiles x 8 row-tiles of W
    const int c4 = tid & 15, rr = tid >> 4;
    #pragma unroll
    for (int p = 0; p < 4; ++p) {
      int row = p * 16 + rr;
      float4 v = reinterpret_cast<const float4*>(W + (size_t)(by * 64 + row) * NCOL + bx * 64)[c4];
      tile[row][c4 * 4 + 0] = v.x; tile[row][c4 * 4 + 1] = v.y;
      tile[row][c4 * 4 + 2] = v.z; tile[row][c4 * 4 + 3] = v.w;
    }
    __syncthreads();
    #pragma unroll
    for (int p = 0; p < 4; ++p) {
      int oc = p * 16 + rr;               // output row (W col)
      unsigned int pk = pack4_fp8(tile[c4 * 4 + 0][oc], tile[c4 * 4 + 1][oc],
                                  tile[c4 * 4 + 2][oc], tile[c4 * 4 + 3][oc]);
      *reinterpret_cast<unsigned int*>(B8 + (size_t)(bx * 64 + oc) * KDIM + by * 64 + c4 * 4) = pk;
    }
  } else if (b < 5632) {
    b -= 5120;
    int rl = tid >> 4, d = tid & 15;
    int row = b * 16 + rl;
    const float4* fr4 = reinterpret_cast<const float4*>(feats + (size_t)row * KDIM);
    float acc = 0.f;
    #pragma unroll 4
    for (int kc = 0; kc < KDIM / 4; ++kc) {
      float4 v = fr4[kc];
      const float* p = proj + (size_t)kc * 64 + d;
      acc += v.x * p[0] + v.y * p[16] + v.z * p[32] + v.w * p[48];
    }
    F[(size_t)row * 16 + d] = acc;        // unnormalized: argmax dot == ref argmin
  } else {
    int r = (b - 5632) * 256 + tid;
    amin[r] = ~0ull;
    rowsum[r] = 0.f;
    if (b == 5632 && tid == 0) out[0] = 0.f;
  }
}

// ---------------- fused: codebook-argmax (first 512 blocks) + GEMM (fp8, 2-deep dbuf) ----------------
#define TGT_BLOCKS 512
#define CB_CODES 128

__device__ __forceinline__ void gld16(const void* g, void* l3) {
  __builtin_amdgcn_global_load_lds((const __attribute__((address_space(1))) void*)g,
                                   (__attribute__((address_space(3))) void*)l3, 16, 0, 0);
}

__global__ __launch_bounds__(256, 4)
void gemm_targets_kernel(const unsigned char* __restrict__ A,  // [MROWS][KDIM] fp8
                         const unsigned char* __restrict__ B,  // [NCOL][KDIM] fp8 (W^T)
                         const float* __restrict__ bias,
                         float* __restrict__ rowsum,
                         const float* __restrict__ F,
                         const float* __restrict__ cb,
                         unsigned long long* __restrict__ amin) {
  __shared__ __align__(16) unsigned char smem[32768];
  const int tid = threadIdx.x;
  const int bid = blockIdx.x;

  if (bid < TGT_BLOCKS) {
    // ---- targets path: block owns 1024 rows x 128 codes; u64 atomicMin merge ----
    float (*csh)[16] = (float (*)[16])smem;
    const int r0 = (bid & 7) * 1024 + tid;
    const int c0 = (bid >> 3) * CB_CODES;
    {
      int ci = tid >> 1, half = tid & 1;
      const float4* src = reinterpret_cast<const float4*>(cb + (size_t)(c0 + ci) * 16 + half * 8);
      float4 v0 = src[0], v1 = src[1];
      float4* dst = reinterpret_cast<float4*>(&csh[ci][half * 8]);
      dst[0] = v0; dst[1] = v1;
    }
    float4 fa[4][4];
    #pragma unroll
    for (int q = 0; q < 4; ++q) {
      const float4* fp = reinterpret_cast<const float4*>(F + (size_t)(r0 + q * 256) * 16);
      fa[q][0] = fp[0]; fa[q][1] = fp[1]; fa[q][2] = fp[2]; fa[q][3] = fp[3];
    }
    __syncthreads();

    float best[4] = {3.4e38f, 3.4e38f, 3.4e38f, 3.4e38f};
    int bidx[4] = {0, 0, 0, 0};
    #pragma unroll 2
    for (int ci = 0; ci < CB_CODES; ++ci) {
      const float4* cvp = reinterpret_cast<const float4*>(&csh[ci][0]);
      float4 c0v = cvp[0], c1v = cvp[1], c2v = cvp[2], c3v = cvp[3];
      #pragma unroll
      for (int q = 0; q < 4; ++q) {
        float dot = fa[q][0].x*c0v.x + fa[q][0].y*c0v.y + fa[q][0].z*c0v.z + fa[q][0].w*c0v.w
                  + fa[q][1].x*c1v.x + fa[q][1].y*c1v.y + fa[q][1].z*c1v.z + fa[q][1].w*c1v.w
                  + fa[q][2].x*c2v.x + fa[q][2].y*c2v.y + fa[q][2].z*c2v.z + fa[q][2].w*c2v.w
                  + fa[q][3].x*c3v.x + fa[q][3].y*c3v.y + fa[q][3].z*c3v.z + fa[q][3].w*c3v.w;
        float d = -dot;
        if (d < best[q]) { best[q] = d; bidx[q] = c0 + ci; }
      }
    }
    #pragma unroll
    for (int q = 0; q < 4; ++q) {
      unsigned int u = __float_as_uint(best[q]);
      unsigned int key = (u & 0x80000000u) ? ~u : (u | 0x80000000u);  // order-preserving
      unsigned long long pk = ((unsigned long long)key << 32) | (unsigned int)bidx[q];
      atomicMin(&amin[r0 + q * 256], pk);
    }
    return;
  }

  // ---- gemm path: 128x128 tile, BK=64, 2-deep LDS double-buffer (R11 measured config) ----
  const int gid = bid - TGT_BLOCKS;
  const int wave = tid >> 6;
  const int lane = tid & 63;
  const int xcd = gid & 7, idx = gid >> 3;
  const int bx = xcd * 8 + (idx & 7);
  const int by = idx >> 3;
  const int row0 = by * 128;
  const int col0 = bx * 128;
  const int wr = wave >> 1, wc = wave & 1;
  unsigned char* As = smem;            // [2 bufs][128 rows][64B]
  unsigned char* Bs = smem + 16384;

  f32x4 acc[4][4];
  #pragma unroll
  for (int i = 0; i < 4; ++i)
    #pragma unroll
    for (int j = 0; j < 4; ++j) acc[i][j] = (f32x4){0.f, 0.f, 0.f, 0.f};

  const int lr = lane >> 2;                               // 16 rows per gld16
  const int lcs = (((lane & 3) ^ ((lane >> 3) & 3)) << 4);// pre-swizzled src 16B slot

  const int l15 = lane & 15, l16 = lane >> 4;
  const int sw = (l15 >> 1) & 3;
  const int subo = (l16 & 1) * 8;
  const int lg16 = l16 >> 1;

  // prologue: stage tile 0 into buf 0
  #pragma unroll
  for (int c = 0; c < 2; ++c) {
    int rchunk = (wave * 2 + c) * 16;
    gld16(A + (size_t)(row0 + rchunk + lr) * KDIM + lcs, As + rchunk * 64);
    gld16(B + (size_t)(col0 + rchunk + lr) * KDIM + lcs, Bs + rchunk * 64);
  }
  __syncthreads();

  #pragma unroll
  for (int t = 0; t < 8; ++t) {
    const int cur = (t & 1) * 8192;
    // prefetch next tile into other buffer; stays in flight during compute
    if (t < 7) {
      const int kt = (t + 1) * 64;
      const int nxt = ((t + 1) & 1) * 8192;
      #pragma unroll
      for (int c = 0; c < 2; ++c) {
        int rchunk = (wave * 2 + c) * 16;
        gld16(A + (size_t)(row0 + rchunk + lr) * KDIM + kt + lcs, As + nxt + rchunk * 64);
        gld16(B + (size_t)(col0 + rchunk + lr) * KDIM + kt + lcs, Bs + nxt + rchunk * 64);
      }
    }
    // compute current buffer
    #pragma unroll
    for (int ks = 0; ks < 2; ++ks) {
      const int poff = (((ks * 2 + lg16) ^ sw) << 4) + subo;
      long af[4], bb[4];
      #pragma unroll
      for (int mi = 0; mi < 4; ++mi)
        af[mi] = *(const long*)(As + cur + (wr * 64 + mi * 16 + l15) * 64 + poff);
      #pragma unroll
      for (int ni = 0; ni < 4; ++ni)
        bb[ni] = *(const long*)(Bs + cur + (wc * 64 + ni * 16 + l15) * 64 + poff);
      #pragma unroll
      for (int mi = 0; mi < 4; ++mi)
        #pragma unroll
        for (int ni = 0; ni < 4; ++ni)
          acc[mi][ni] = __builtin_amdgcn_mfma_f32_16x16x32_fp8_fp8(af[mi], bb[ni], acc[mi][ni], 0, 0, 0);
    }
    if (t < 7) __syncthreads();
  }

  // slim epilogue: per-row partial sum(exp(logit))
  float bv[4];
  #pragma unroll
  for (int ni = 0; ni < 4; ++ni)
    bv[ni] = bias[col0 + wc * 64 + ni * 16 + l15];
  #pragma unroll
  for (int mi = 0; mi < 4; ++mi) {
    int rbase = row0 + wr * 64 + mi * 16 + l16 * 4;
    #pragma unroll
    for (int j = 0; j < 4; ++j) {
      float se = 0.f;
      #pragma unroll
      for (int ni = 0; ni < 4; ++ni)
        se += __expf(acc[mi][ni][j] + bv[ni]);
      #pragma unroll
      for (int o = 1; o < 16; o <<= 1) se += __shfl_xor(se, o);
      if (l15 == 0) atomicAdd(&rowsum[rbase + j], se);
    }
  }
}

// ---------------- merged: target logit + masked-mean loss ----------------
// 64 blocks x 256; each wave handles 32 rows; atomicAdd pre-scaled nll.
__global__ void tgtloss_kernel(const unsigned char* __restrict__ A,
                               const unsigned char* __restrict__ B,
                               const float* __restrict__ bias,
                               const unsigned long long* __restrict__ amin,
                               const float* __restrict__ rowsum,
                               const int* __restrict__ lens,
                               float* __restrict__ out) {
  __shared__ float sp[4];
  const int wave = threadIdx.x >> 6, lane = threadIdx.x & 63;
  const int cnt = lens[0] + lens[1] + lens[2] + lens[3];
  const float inv = 1.0f / (float)max(cnt, 1);
  float partial = 0.f;
  #pragma unroll 4
  for (int i = 0; i < 32; ++i) {
    const int r = blockIdx.x * 128 + wave * 32 + i;
    const int tg = (int)(amin[r] & 0xffffffffull);
    uint2 ua = reinterpret_cast<const uint2*>(A + (size_t)r * KDIM)[lane];
    uint2 ub = reinterpret_cast<const uint2*>(B + (size_t)tg * KDIM)[lane];
    float s = 0.f;
    const unsigned char* pa = reinterpret_cast<const unsigned char*>(&ua);
    const unsigned char* pb = reinterpret_cast<const unsigned char*>(&ub);
    #pragma unroll
    for (int k = 0; k < 8; ++k) s += fp8d(pa[k]) * fp8d(pb[k]);
    #pragma unroll
    for (int o = 1; o < 64; o <<= 1) s += __shfl_xor(s, o);
    const int n = r >> 11, t = r & (TSEQ - 1);
    if (lane == 0 && t < lens[n])
      partial += logf(rowsum[r]) - (s + bias[tg]);
  }
  if (lane == 0) sp[wave] = partial;
  __syncthreads();
  if (threadIdx.x == 0)
    atomicAdd(out, (sp[0] + sp[1] + sp[2] + sp[3]) * inv);
}

extern "C" void kernel_launch(void* const* d_in, const int* in_sizes, int n_in,
                              void* d_out, int out_size, void* d_ws, size_t ws_size,
                              hipStream_t stream) {
  const float* feats    = (const float*)d_in[0];
  const float* context  = (const float*)d_in[1];
  const int*   lens     = (const int*)d_in[2];
  const float* proj     = (const float*)d_in[3];
  const float* codebook = (const float*)d_in[4];
  const float* W_enc    = (const float*)d_in[5];
  const float* b_enc    = (const float*)d_in[6];
  float* out = (float*)d_out;

  char* ws = (char*)d_ws;
  unsigned char* A8 = (unsigned char*)(ws);                       // 4 MB
  unsigned char* B8 = (unsigned char*)(ws + 4194304);             // 4 MB
  float* F          = (float*)(ws + 8388608);                     // 512 KB
  unsigned long long* amin = (unsigned long long*)(ws + 8912896); // 64 KB
  float* rowsum     = (float*)(ws + 8978432);                     // 32 KB

  // 1) conversions + projection + init (also zeroes out[0])
  prep_kernel<<<5664, 256, 0, stream>>>(context, A8, W_enc, B8, feats, proj, F, amin, rowsum, out);
  // 2) codebook argmax (first 512 blocks)  ||  GEMM(2-deep dbuf)+rowsum(exp)
  gemm_targets_kernel<<<TGT_BLOCKS + 4096, 256, 0, stream>>>(A8, B8, b_enc, rowsum, F, codebook, amin);
  // 3) target logit + masked-mean loss
  tgtloss_kernel<<<64, 256, 0, stream>>>(A8, B8, b_enc, amin, rowsum, lens, out);
}

// Round 15
// 188.502 us; speedup vs baseline: 1.2904x; 1.1274x over previous
//
#include <hip/hip_runtime.h>
#include <hip/hip_bf16.h>
#include <hip/hip_fp8.h>

#define MROWS 8192   // N*T
#define KDIM  512    // CIN
#define NCOL  8192   // codebook size K
#define TSEQ  2048

typedef float f32x4 __attribute__((ext_vector_type(4)));

__device__ __forceinline__ unsigned int pack4_fp8(float a, float b, float c, float d) {
#if __has_builtin(__builtin_amdgcn_cvt_pk_fp8_f32)
  int r = __builtin_amdgcn_cvt_pk_fp8_f32(a, b, 0, false);
  r = __builtin_amdgcn_cvt_pk_fp8_f32(c, d, r, true);
  return (unsigned int)r;
#else
  __hip_fp8_e4m3 ha(a), hb(b), hc(c), hd(d);
  return (unsigned int)ha.__x | ((unsigned int)hb.__x << 8) |
         ((unsigned int)hc.__x << 16) | ((unsigned int)hd.__x << 24);
#endif
}

// exact OCP e4m3 decode
__device__ __forceinline__ float fp8d(unsigned char b) {
  unsigned int s = b >> 7, e = (b >> 3) & 15, m = b & 7;
  if (e == 0) {
    float v = (float)m * 0.001953125f;
    return s ? -v : v;
  }
  unsigned int bits = (s << 31) | ((e + 120) << 23) | (m << 20);
  return __uint_as_float(bits);
}

// ---------------- prep: convA, convB-transpose, fproj (no normalize), init ----------------
// [0,4096): convA   [4096,5120): convB   [5120,5632): fproj   [5632,5664): init amin/rowsum/out
__global__ void prep_kernel(const float* __restrict__ X, unsigned char* __restrict__ A8,
                            const float* __restrict__ W, unsigned char* __restrict__ B8,
                            const float* __restrict__ feats, const float* __restrict__ proj,
                            float* __restrict__ F, unsigned long long* __restrict__ amin,
                            float* __restrict__ rowsum, float* __restrict__ out) {
  __shared__ float tile[64][65];
  const int tid = threadIdx.x;
  int b = blockIdx.x;
  if (b < 4096) {
    int i = b * 256 + tid;                 // float4 index
    float4 v = reinterpret_cast<const float4*>(X)[i];
    reinterpret_cast<unsigned int*>(A8)[i] = pack4_fp8(v.x, v.y, v.z, v.w);
  } else if (b < 5120) {
    b -= 4096;
    const int bx = b & 127, by = b >> 7;    // 128 col-tiles x 8 row-tiles of W
    const int c4 = tid & 15, rr = tid >> 4;
    #pragma unroll
    for (int p = 0; p < 4; ++p) {
      int row = p * 16 + rr;
      float4 v = reinterpret_cast<const float4*>(W + (size_t)(by * 64 + row) * NCOL + bx * 64)[c4];
      tile[row][c4 * 4 + 0] = v.x; tile[row][c4 * 4 + 1] = v.y;
      tile[row][c4 * 4 + 2] = v.z; tile[row][c4 * 4 + 3] = v.w;
    }
    __syncthreads();
    #pragma unroll
    for (int p = 0; p < 4; ++p) {
      int oc = p * 16 + rr;               // output row (W col)
      unsigned int pk = pack4_fp8(tile[c4 * 4 + 0][oc], tile[c4 * 4 + 1][oc],
                                  tile[c4 * 4 + 2][oc], tile[c4 * 4 + 3][oc]);
      *reinterpret_cast<unsigned int*>(B8 + (size_t)(bx * 64 + oc) * KDIM + by * 64 + c4 * 4) = pk;
    }
  } else if (b < 5632) {
    b -= 5120;
    int rl = tid >> 4, d = tid & 15;
    int row = b * 16 + rl;
    const float4* fr4 = reinterpret_cast<const float4*>(feats + (size_t)row * KDIM);
    float acc = 0.f;
    #pragma unroll 4
    for (int kc = 0; kc < KDIM / 4; ++kc) {
      float4 v = fr4[kc];
      const float* p = proj + (size_t)kc * 64 + d;
      acc += v.x * p[0] + v.y * p[16] + v.z * p[32] + v.w * p[48];
    }
    F[(size_t)row * 16 + d] = acc;        // unnormalized: argmax dot == ref argmin
  } else {
    int r = (b - 5632) * 256 + tid;
    amin[r] = ~0ull;
    rowsum[r] = 0.f;
    if (b == 5632 && tid == 0) out[0] = 0.f;
  }
}

// ---------------- fused: codebook-argmax (first 512 blocks) + GEMM (fp8, 2-deep dbuf) ----------------
#define TGT_BLOCKS 512
#define CB_CODES 128

__device__ __forceinline__ void gld16(const void* g, void* l3) {
  __builtin_amdgcn_global_load_lds((const __attribute__((address_space(1))) void*)g,
                                   (__attribute__((address_space(3))) void*)l3, 16, 0, 0);
}

__global__ __launch_bounds__(256, 4)
void gemm_targets_kernel(const unsigned char* __restrict__ A,  // [MROWS][KDIM] fp8
                         const unsigned char* __restrict__ B,  // [NCOL][KDIM] fp8 (W^T)
                         const float* __restrict__ bias,
                         float* __restrict__ rowsum,
                         const float* __restrict__ F,
                         const float* __restrict__ cb,
                         unsigned long long* __restrict__ amin) {
  __shared__ __align__(16) unsigned char smem[32768];
  const int tid = threadIdx.x;
  const int bid = blockIdx.x;

  if (bid < TGT_BLOCKS) {
    // ---- targets path: block owns 1024 rows x 128 codes; u64 atomicMin merge ----
    float (*csh)[16] = (float (*)[16])smem;
    const int r0 = (bid & 7) * 1024 + tid;
    const int c0 = (bid >> 3) * CB_CODES;
    {
      int ci = tid >> 1, half = tid & 1;
      const float4* src = reinterpret_cast<const float4*>(cb + (size_t)(c0 + ci) * 16 + half * 8);
      float4 v0 = src[0], v1 = src[1];
      float4* dst = reinterpret_cast<float4*>(&csh[ci][half * 8]);
      dst[0] = v0; dst[1] = v1;
    }
    float4 fa[4][4];
    #pragma unroll
    for (int q = 0; q < 4; ++q) {
      const float4* fp = reinterpret_cast<const float4*>(F + (size_t)(r0 + q * 256) * 16);
      fa[q][0] = fp[0]; fa[q][1] = fp[1]; fa[q][2] = fp[2]; fa[q][3] = fp[3];
    }
    __syncthreads();

    float best[4] = {3.4e38f, 3.4e38f, 3.4e38f, 3.4e38f};
    int bidx[4] = {0, 0, 0, 0};
    #pragma unroll 2
    for (int ci = 0; ci < CB_CODES; ++ci) {
      const float4* cvp = reinterpret_cast<const float4*>(&csh[ci][0]);
      float4 c0v = cvp[0], c1v = cvp[1], c2v = cvp[2], c3v = cvp[3];
      #pragma unroll
      for (int q = 0; q < 4; ++q) {
        float dot = fa[q][0].x*c0v.x + fa[q][0].y*c0v.y + fa[q][0].z*c0v.z + fa[q][0].w*c0v.w
                  + fa[q][1].x*c1v.x + fa[q][1].y*c1v.y + fa[q][1].z*c1v.z + fa[q][1].w*c1v.w
                  + fa[q][2].x*c2v.x + fa[q][2].y*c2v.y + fa[q][2].z*c2v.z + fa[q][2].w*c2v.w
                  + fa[q][3].x*c3v.x + fa[q][3].y*c3v.y + fa[q][3].z*c3v.z + fa[q][3].w*c3v.w;
        float d = -dot;
        if (d < best[q]) { best[q] = d; bidx[q] = c0 + ci; }
      }
    }
    #pragma unroll
    for (int q = 0; q < 4; ++q) {
      unsigned int u = __float_as_uint(best[q]);
      unsigned int key = (u & 0x80000000u) ? ~u : (u | 0x80000000u);  // order-preserving
      unsigned long long pk = ((unsigned long long)key << 32) | (unsigned int)bidx[q];
      atomicMin(&amin[r0 + q * 256], pk);
    }
    return;
  }

  // ---- gemm path: 128x128 tile, BK=64, 2-deep LDS double-buffer (R11 measured config) ----
  const int gid = bid - TGT_BLOCKS;
  const int wave = tid >> 6;
  const int lane = tid & 63;
  const int xcd = gid & 7, idx = gid >> 3;
  const int bx = xcd * 8 + (idx & 7);
  const int by = idx >> 3;
  const int row0 = by * 128;
  const int col0 = bx * 128;
  const int wr = wave >> 1, wc = wave & 1;
  unsigned char* As = smem;            // [2 bufs][128 rows][64B]
  unsigned char* Bs = smem + 16384;

  f32x4 acc[4][4];
  #pragma unroll
  for (int i = 0; i < 4; ++i)
    #pragma unroll
    for (int j = 0; j < 4; ++j) acc[i][j] = (f32x4){0.f, 0.f, 0.f, 0.f};

  const int lr = lane >> 2;                               // 16 rows per gld16
  const int lcs = (((lane & 3) ^ ((lane >> 3) & 3)) << 4);// pre-swizzled src 16B slot

  const int l15 = lane & 15, l16 = lane >> 4;
  const int sw = (l15 >> 1) & 3;
  const int subo = (l16 & 1) * 8;
  const int lg16 = l16 >> 1;

  // prologue: stage tile 0 into buf 0
  #pragma unroll
  for (int c = 0; c < 2; ++c) {
    int rchunk = (wave * 2 + c) * 16;
    gld16(A + (size_t)(row0 + rchunk + lr) * KDIM + lcs, As + rchunk * 64);
    gld16(B + (size_t)(col0 + rchunk + lr) * KDIM + lcs, Bs + rchunk * 64);
  }
  __syncthreads();

  #pragma unroll
  for (int t = 0; t < 8; ++t) {
    const int cur = (t & 1) * 8192;
    // prefetch next tile into other buffer; stays in flight during compute
    if (t < 7) {
      const int kt = (t + 1) * 64;
      const int nxt = ((t + 1) & 1) * 8192;
      #pragma unroll
      for (int c = 0; c < 2; ++c) {
        int rchunk = (wave * 2 + c) * 16;
        gld16(A + (size_t)(row0 + rchunk + lr) * KDIM + kt + lcs, As + nxt + rchunk * 64);
        gld16(B + (size_t)(col0 + rchunk + lr) * KDIM + kt + lcs, Bs + nxt + rchunk * 64);
      }
    }
    // compute current buffer
    #pragma unroll
    for (int ks = 0; ks < 2; ++ks) {
      const int poff = (((ks * 2 + lg16) ^ sw) << 4) + subo;
      long af[4], bb[4];
      #pragma unroll
      for (int mi = 0; mi < 4; ++mi)
        af[mi] = *(const long*)(As + cur + (wr * 64 + mi * 16 + l15) * 64 + poff);
      #pragma unroll
      for (int ni = 0; ni < 4; ++ni)
        bb[ni] = *(const long*)(Bs + cur + (wc * 64 + ni * 16 + l15) * 64 + poff);
      #pragma unroll
      for (int mi = 0; mi < 4; ++mi)
        #pragma unroll
        for (int ni = 0; ni < 4; ++ni)
          acc[mi][ni] = __builtin_amdgcn_mfma_f32_16x16x32_fp8_fp8(af[mi], bb[ni], acc[mi][ni], 0, 0, 0);
    }
    if (t < 7) __syncthreads();
  }

  // slim epilogue: per-row partial sum(exp(logit))
  float bv[4];
  #pragma unroll
  for (int ni = 0; ni < 4; ++ni)
    bv[ni] = bias[col0 + wc * 64 + ni * 16 + l15];
  #pragma unroll
  for (int mi = 0; mi < 4; ++mi) {
    int rbase = row0 + wr * 64 + mi * 16 + l16 * 4;
    #pragma unroll
    for (int j = 0; j < 4; ++j) {
      float se = 0.f;
      #pragma unroll
      for (int ni = 0; ni < 4; ++ni)
        se += __expf(acc[mi][ni][j] + bv[ni]);
      #pragma unroll
      for (int o = 1; o < 16; o <<= 1) se += __shfl_xor(se, o);
      if (l15 == 0) atomicAdd(&rowsum[rbase + j], se);
    }
  }
}

// ---------------- merged: target logit + masked-mean loss ----------------
// 2048 blocks x 4 waves; one row per wave; one atomicAdd per block.
__global__ void tgtloss_kernel(const unsigned char* __restrict__ A,
                               const unsigned char* __restrict__ B,
                               const float* __restrict__ bias,
                               const unsigned long long* __restrict__ amin,
                               const float* __restrict__ rowsum,
                               const int* __restrict__ lens,
                               float* __restrict__ out) {
  __shared__ float sp[4];
  const int wave = threadIdx.x >> 6, lane = threadIdx.x & 63;
  const int cnt = lens[0] + lens[1] + lens[2] + lens[3];
  const float inv = 1.0f / (float)max(cnt, 1);
  const int r = blockIdx.x * 4 + wave;
  const int tg = (int)(amin[r] & 0xffffffffull);
  uint2 ua = reinterpret_cast<const uint2*>(A + (size_t)r * KDIM)[lane];
  uint2 ub = reinterpret_cast<const uint2*>(B + (size_t)tg * KDIM)[lane];
  float s = 0.f;
  const unsigned char* pa = reinterpret_cast<const unsigned char*>(&ua);
  const unsigned char* pb = reinterpret_cast<const unsigned char*>(&ub);
  #pragma unroll
  for (int k = 0; k < 8; ++k) s += fp8d(pa[k]) * fp8d(pb[k]);
  #pragma unroll
  for (int o = 1; o < 64; o <<= 1) s += __shfl_xor(s, o);
  if (lane == 0) {
    const int n = r >> 11, t = r & (TSEQ - 1);
    sp[wave] = (t < lens[n]) ? (logf(rowsum[r]) - (s + bias[tg])) * inv : 0.f;
  }
  __syncthreads();
  if (threadIdx.x == 0)
    atomicAdd(out, sp[0] + sp[1] + sp[2] + sp[3]);
}

extern "C" void kernel_launch(void* const* d_in, const int* in_sizes, int n_in,
                              void* d_out, int out_size, void* d_ws, size_t ws_size,
                              hipStream_t stream) {
  const float* feats    = (const float*)d_in[0];
  const float* context  = (const float*)d_in[1];
  const int*   lens     = (const int*)d_in[2];
  const float* proj     = (const float*)d_in[3];
  const float* codebook = (const float*)d_in[4];
  const float* W_enc    = (const float*)d_in[5];
  const float* b_enc    = (const float*)d_in[6];
  float* out = (float*)d_out;

  char* ws = (char*)d_ws;
  unsigned char* A8 = (unsigned char*)(ws);                       // 4 MB
  unsigned char* B8 = (unsigned char*)(ws + 4194304);             // 4 MB
  float* F          = (float*)(ws + 8388608);                     // 512 KB
  unsigned long long* amin = (unsigned long long*)(ws + 8912896); // 64 KB
  float* rowsum     = (float*)(ws + 8978432);                     // 32 KB

  // 1) conversions + projection + init (also zeroes out[0])
  prep_kernel<<<5664, 256, 0, stream>>>(context, A8, W_enc, B8, feats, proj, F, amin, rowsum, out);
  // 2) codebook argmax (first 512 blocks)  ||  GEMM(2-deep dbuf)+rowsum(exp)
  gemm_targets_kernel<<<TGT_BLOCKS + 4096, 256, 0, stream>>>(A8, B8, b_enc, rowsum, F, codebook, amin);
  // 3) target logit + masked-mean loss
  tgtloss_kernel<<<2048, 256, 0, stream>>>(A8, B8, b_enc, amin, rowsum, lens, out);
}

// Round 16
// 180.242 us; speedup vs baseline: 1.3495x; 1.0458x over previous
//
#include <hip/hip_runtime.h>
#include <hip/hip_bf16.h>
#include <hip/hip_fp8.h>

#define MROWS 8192   // N*T
#define KDIM  512    // CIN
#define NCOL  8192   // codebook size K
#define TSEQ  2048

typedef float f32x4 __attribute__((ext_vector_type(4)));
typedef long  lx2  __attribute__((ext_vector_type(2)));

__device__ __forceinline__ unsigned int pack4_fp8(float a, float b, float c, float d) {
#if __has_builtin(__builtin_amdgcn_cvt_pk_fp8_f32)
  int r = __builtin_amdgcn_cvt_pk_fp8_f32(a, b, 0, false);
  r = __builtin_amdgcn_cvt_pk_fp8_f32(c, d, r, true);
  return (unsigned int)r;
#else
  __hip_fp8_e4m3 ha(a), hb(b), hc(c), hd(d);
  return (unsigned int)ha.__x | ((unsigned int)hb.__x << 8) |
         ((unsigned int)hc.__x << 16) | ((unsigned int)hd.__x << 24);
#endif
}

// exact OCP e4m3 decode
__device__ __forceinline__ float fp8d(unsigned char b) {
  unsigned int s = b >> 7, e = (b >> 3) & 15, m = b & 7;
  if (e == 0) {
    float v = (float)m * 0.001953125f;
    return s ? -v : v;
  }
  unsigned int bits = (s << 31) | ((e + 120) << 23) | (m << 20);
  return __uint_as_float(bits);
}

// Fragment-packed layout: for row-group g=r>>4, K-tile t=kb>>6, the 1KB chunk at
// (g*8+t)*1024 holds 64 lanes x 16B; lane (l16*16+l15) holds k-bytes
// [t*64 + 0*32 + l16*8 .. +8) in its low 8B and [t*64 + 32 + l16*8 .. +8) high.
// Byte (r, kb) -> chunk (g,t), lane slot via l16=(kb&31)>>3, half ks=(kb&63)>>5.
__device__ __forceinline__ size_t pk_addr(int r, int kb) {
  int t = kb >> 6, tb = kb & 63;
  int ks = tb >> 5, rem = tb & 31;
  int l16 = rem >> 3, bo = rem & 7;
  return ((size_t)(((r >> 4) << 3) + t) << 10) + (((l16 << 4) + (r & 15)) << 4) + (ks << 3) + bo;
}

// ---------------- prep: convA, convB-transpose, fproj, init (all to packed layout) ----------------
// [0,4096): convA   [4096,5120): convB   [5120,5632): fproj   [5632,5664): init amin/rowsum/out
__global__ void prep_kernel(const float* __restrict__ X, unsigned char* __restrict__ A8,
                            const float* __restrict__ W, unsigned char* __restrict__ B8,
                            const float* __restrict__ feats, const float* __restrict__ proj,
                            float* __restrict__ F, unsigned long long* __restrict__ amin,
                            float* __restrict__ rowsum, float* __restrict__ out) {
  __shared__ float tile[64][65];
  const int tid = threadIdx.x;
  int b = blockIdx.x;
  if (b < 4096) {
    int i = b * 256 + tid;                 // float4 index over rows of context
    int r = i >> 7;                        // 128 float4 per row
    int kb = (i & 127) << 2;               // starting k-byte (4B aligned, within 8B half)
    float4 v = reinterpret_cast<const float4*>(X)[i];
    unsigned int pk = pack4_fp8(v.x, v.y, v.z, v.w);
    *reinterpret_cast<unsigned int*>(A8 + pk_addr(r, kb)) = pk;
  } else if (b < 5120) {
    b -= 4096;
    const int bx = b & 127, by = b >> 7;    // 128 col-tiles x 8 row-tiles of W
    const int c4 = tid & 15, rr = tid >> 4;
    #pragma unroll
    for (int p = 0; p < 4; ++p) {
      int row = p * 16 + rr;
      float4 v = reinterpret_cast<const float4*>(W + (size_t)(by * 64 + row) * NCOL + bx * 64)[c4];
      tile[row][c4 * 4 + 0] = v.x; tile[row][c4 * 4 + 1] = v.y;
      tile[row][c4 * 4 + 2] = v.z; tile[row][c4 * 4 + 3] = v.w;
    }
    __syncthreads();
    #pragma unroll
    for (int p = 0; p < 4; ++p) {
      int oc = p * 16 + rr;               // output row (W col)
      unsigned int pk = pack4_fp8(tile[c4 * 4 + 0][oc], tile[c4 * 4 + 1][oc],
                                  tile[c4 * 4 + 2][oc], tile[c4 * 4 + 3][oc]);
      *reinterpret_cast<unsigned int*>(B8 + pk_addr(bx * 64 + oc, by * 64 + c4 * 4)) = pk;
    }
  } else if (b < 5632) {
    b -= 5120;
    int rl = tid >> 4, d = tid & 15;
    int row = b * 16 + rl;
    const float4* fr4 = reinterpret_cast<const float4*>(feats + (size_t)row * KDIM);
    float acc = 0.f;
    #pragma unroll 4
    for (int kc = 0; kc < KDIM / 4; ++kc) {
      float4 v = fr4[kc];
      const float* p = proj + (size_t)kc * 64 + d;
      acc += v.x * p[0] + v.y * p[16] + v.z * p[32] + v.w * p[48];
    }
    F[(size_t)row * 16 + d] = acc;        // unnormalized: argmax dot == ref argmin
  } else {
    int r = (b - 5632) * 256 + tid;
    amin[r] = ~0ull;
    rowsum[r] = 0.f;
    if (b == 5632 && tid == 0) out[0] = 0.f;
  }
}

// ---------------- fused: codebook-argmax (first 512 blocks) + barrier-free reg-direct GEMM ----------------
#define TGT_BLOCKS 512
#define CB_CODES 128

__global__ __launch_bounds__(256, 3)
void gemm_targets_kernel(const unsigned char* __restrict__ A,  // packed fp8 fragments
                         const unsigned char* __restrict__ B,  // packed fp8 fragments (W^T)
                         const float* __restrict__ bias,
                         float* __restrict__ rowsum,
                         const float* __restrict__ F,
                         const float* __restrict__ cb,
                         unsigned long long* __restrict__ amin) {
  __shared__ __align__(16) float csh[CB_CODES][16];
  const int tid = threadIdx.x;
  const int bid = blockIdx.x;

  if (bid < TGT_BLOCKS) {
    // ---- targets path: block owns 1024 rows x 128 codes; u64 atomicMin merge ----
    const int r0 = (bid & 7) * 1024 + tid;
    const int c0 = (bid >> 3) * CB_CODES;
    {
      int ci = tid >> 1, half = tid & 1;
      const float4* src = reinterpret_cast<const float4*>(cb + (size_t)(c0 + ci) * 16 + half * 8);
      float4 v0 = src[0], v1 = src[1];
      float4* dst = reinterpret_cast<float4*>(&csh[ci][half * 8]);
      dst[0] = v0; dst[1] = v1;
    }
    float4 fa[4][4];
    #pragma unroll
    for (int q = 0; q < 4; ++q) {
      const float4* fp = reinterpret_cast<const float4*>(F + (size_t)(r0 + q * 256) * 16);
      fa[q][0] = fp[0]; fa[q][1] = fp[1]; fa[q][2] = fp[2]; fa[q][3] = fp[3];
    }
    __syncthreads();

    float best[4] = {3.4e38f, 3.4e38f, 3.4e38f, 3.4e38f};
    int bidx[4] = {0, 0, 0, 0};
    #pragma unroll 2
    for (int ci = 0; ci < CB_CODES; ++ci) {
      const float4* cvp = reinterpret_cast<const float4*>(&csh[ci][0]);
      float4 c0v = cvp[0], c1v = cvp[1], c2v = cvp[2], c3v = cvp[3];
      #pragma unroll
      for (int q = 0; q < 4; ++q) {
        float dot = fa[q][0].x*c0v.x + fa[q][0].y*c0v.y + fa[q][0].z*c0v.z + fa[q][0].w*c0v.w
                  + fa[q][1].x*c1v.x + fa[q][1].y*c1v.y + fa[q][1].z*c1v.z + fa[q][1].w*c1v.w
                  + fa[q][2].x*c2v.x + fa[q][2].y*c2v.y + fa[q][2].z*c2v.z + fa[q][2].w*c2v.w
                  + fa[q][3].x*c3v.x + fa[q][3].y*c3v.y + fa[q][3].z*c3v.z + fa[q][3].w*c3v.w;
        float d = -dot;
        if (d < best[q]) { best[q] = d; bidx[q] = c0 + ci; }
      }
    }
    #pragma unroll
    for (int q = 0; q < 4; ++q) {
      unsigned int u = __float_as_uint(best[q]);
      unsigned int key = (u & 0x80000000u) ? ~u : (u | 0x80000000u);  // order-preserving
      unsigned long long pk = ((unsigned long long)key << 32) | (unsigned int)bidx[q];
      atomicMin(&amin[r0 + q * 256], pk);
    }
    return;
  }

  // ---- gemm path: 128x128 tile, reg-direct fragments, NO LDS, NO barriers ----
  const int gid = bid - TGT_BLOCKS;
  const int wave = tid >> 6;
  const int lane = tid & 63;
  const int xcd = gid & 7, idx = gid >> 3;
  const int bx = xcd * 8 + (idx & 7);
  const int by = idx >> 3;
  const int row0 = by * 128;
  const int col0 = bx * 128;
  const int wr = wave >> 1, wc = wave & 1;

  f32x4 acc[4][4];
  #pragma unroll
  for (int i = 0; i < 4; ++i)
    #pragma unroll
    for (int j = 0; j < 4; ++j) acc[i][j] = (f32x4){0.f, 0.f, 0.f, 0.f};

  // fragment chunk bases: group g spans 8 K-tiles x 1KB = 8KB
  const unsigned char* abase[4];
  const unsigned char* bbase[4];
  #pragma unroll
  for (int mi = 0; mi < 4; ++mi)
    abase[mi] = A + ((size_t)((row0 >> 4) + wr * 4 + mi) << 13) + lane * 16;
  #pragma unroll
  for (int ni = 0; ni < 4; ++ni)
    bbase[ni] = B + ((size_t)((col0 >> 4) + wc * 4 + ni) << 13) + lane * 16;

  #pragma unroll
  for (int t = 0; t < 8; ++t) {
    lx2 afr[4], bfr[4];
    #pragma unroll
    for (int mi = 0; mi < 4; ++mi)
      afr[mi] = *reinterpret_cast<const lx2*>(abase[mi] + t * 1024);
    #pragma unroll
    for (int ni = 0; ni < 4; ++ni)
      bfr[ni] = *reinterpret_cast<const lx2*>(bbase[ni] + t * 1024);
    #pragma unroll
    for (int mi = 0; mi < 4; ++mi)
      #pragma unroll
      for (int ni = 0; ni < 4; ++ni) {
        acc[mi][ni] = __builtin_amdgcn_mfma_f32_16x16x32_fp8_fp8(afr[mi][0], bfr[ni][0], acc[mi][ni], 0, 0, 0);
        acc[mi][ni] = __builtin_amdgcn_mfma_f32_16x16x32_fp8_fp8(afr[mi][1], bfr[ni][1], acc[mi][ni], 0, 0, 0);
      }
  }

  // slim epilogue: per-row partial sum(exp(logit))
  const int l15 = lane & 15, l16 = lane >> 4;
  float bv[4];
  #pragma unroll
  for (int ni = 0; ni < 4; ++ni)
    bv[ni] = bias[col0 + wc * 64 + ni * 16 + l15];
  #pragma unroll
  for (int mi = 0; mi < 4; ++mi) {
    int rbase = row0 + wr * 64 + mi * 16 + l16 * 4;
    #pragma unroll
    for (int j = 0; j < 4; ++j) {
      float se = 0.f;
      #pragma unroll
      for (int ni = 0; ni < 4; ++ni)
        se += __expf(acc[mi][ni][j] + bv[ni]);
      #pragma unroll
      for (int o = 1; o < 16; o <<= 1) se += __shfl_xor(se, o);
      if (l15 == 0) atomicAdd(&rowsum[rbase + j], se);
    }
  }
}

// ---------------- merged: target logit + masked-mean loss (packed-layout gather) ----------------
// 2048 blocks x 4 waves; one row per wave; one atomicAdd per block.
__global__ void tgtloss_kernel(const unsigned char* __restrict__ A,
                               const unsigned char* __restrict__ B,
                               const float* __restrict__ bias,
                               const unsigned long long* __restrict__ amin,
                               const float* __restrict__ rowsum,
                               const int* __restrict__ lens,
                               float* __restrict__ out) {
  __shared__ float sp[4];
  const int wave = threadIdx.x >> 6, lane = threadIdx.x & 63;
  const int cnt = lens[0] + lens[1] + lens[2] + lens[3];
  const float inv = 1.0f / (float)max(cnt, 1);
  const int r = blockIdx.x * 4 + wave;
  const int tg = (int)(amin[r] & 0xffffffffull);
  // lane covers k-bytes [lane*8, lane*8+8)
  const int kb = lane << 3;
  uint2 ua = *reinterpret_cast<const uint2*>(A + pk_addr(r, kb));
  uint2 ub = *reinterpret_cast<const uint2*>(B + pk_addr(tg, kb));
  float s = 0.f;
  const unsigned char* pa = reinterpret_cast<const unsigned char*>(&ua);
  const unsigned char* pb = reinterpret_cast<const unsigned char*>(&ub);
  #pragma unroll
  for (int k = 0; k < 8; ++k) s += fp8d(pa[k]) * fp8d(pb[k]);
  #pragma unroll
  for (int o = 1; o < 64; o <<= 1) s += __shfl_xor(s, o);
  if (lane == 0) {
    const int n = r >> 11, t = r & (TSEQ - 1);
    sp[wave] = (t < lens[n]) ? (logf(rowsum[r]) - (s + bias[tg])) * inv : 0.f;
  }
  __syncthreads();
  if (threadIdx.x == 0)
    atomicAdd(out, sp[0] + sp[1] + sp[2] + sp[3]);
}

extern "C" void kernel_launch(void* const* d_in, const int* in_sizes, int n_in,
                              void* d_out, int out_size, void* d_ws, size_t ws_size,
                              hipStream_t stream) {
  const float* feats    = (const float*)d_in[0];
  const float* context  = (const float*)d_in[1];
  const int*   lens     = (const int*)d_in[2];
  const float* proj     = (const float*)d_in[3];
  const float* codebook = (const float*)d_in[4];
  const float* W_enc    = (const float*)d_in[5];
  const float* b_enc    = (const float*)d_in[6];
  float* out = (float*)d_out;

  char* ws = (char*)d_ws;
  unsigned char* A8 = (unsigned char*)(ws);                       // 4 MB (packed)
  unsigned char* B8 = (unsigned char*)(ws + 4194304);             // 4 MB (packed)
  float* F          = (float*)(ws + 8388608);                     // 512 KB
  unsigned long long* amin = (unsigned long long*)(ws + 8912896); // 64 KB
  float* rowsum     = (float*)(ws + 8978432);                     // 32 KB

  // 1) conversions (fragment-packed) + projection + init (also zeroes out[0])
  prep_kernel<<<5664, 256, 0, stream>>>(context, A8, W_enc, B8, feats, proj, F, amin, rowsum, out);
  // 2) codebook argmax (first 512 blocks)  ||  barrier-free GEMM + rowsum(exp)
  gemm_targets_kernel<<<TGT_BLOCKS + 4096, 256, 0, stream>>>(A8, B8, b_enc, rowsum, F, codebook, amin);
  // 3) target logit + masked-mean loss
  tgtloss_kernel<<<2048, 256, 0, stream>>>(A8, B8, b_enc, amin, rowsum, lens, out);
}

// Round 17
// 165.287 us; speedup vs baseline: 1.4716x; 1.0905x over previous
//
#include <hip/hip_runtime.h>
#include <hip/hip_bf16.h>
#include <hip/hip_fp8.h>

#define MROWS 8192   // N*T
#define KDIM  512    // CIN
#define NCOL  8192   // codebook size K
#define TSEQ  2048

typedef float f32x4 __attribute__((ext_vector_type(4)));
typedef long  lx2  __attribute__((ext_vector_type(2)));

__device__ __forceinline__ unsigned int pack4_fp8(float a, float b, float c, float d) {
#if __has_builtin(__builtin_amdgcn_cvt_pk_fp8_f32)
  int r = __builtin_amdgcn_cvt_pk_fp8_f32(a, b, 0, false);
  r = __builtin_amdgcn_cvt_pk_fp8_f32(c, d, r, true);
  return (unsigned int)r;
#else
  __hip_fp8_e4m3 ha(a), hb(b), hc(c), hd(d);
  return (unsigned int)ha.__x | ((unsigned int)hb.__x << 8) |
         ((unsigned int)hc.__x << 16) | ((unsigned int)hd.__x << 24);
#endif
}

// exact OCP e4m3 decode
__device__ __forceinline__ float fp8d(unsigned char b) {
  unsigned int s = b >> 7, e = (b >> 3) & 15, m = b & 7;
  if (e == 0) {
    float v = (float)m * 0.001953125f;
    return s ? -v : v;
  }
  unsigned int bits = (s << 31) | ((e + 120) << 23) | (m << 20);
  return __uint_as_float(bits);
}

// Fragment-packed layout: chunk id = (row_group * 8 + k_tile); 1KB chunk holds
// 64 lanes x 16B. Lane slot s = l16*16 + l15 (l16 = k-subgroup, l15 = row%16).
// Lane's 16B: low 8B = k bytes [t*64 + l16*8 .. +8), high 8B = [t*64+32+l16*8 .. +8).
__device__ __forceinline__ size_t pk_addr(int r, int kb) {
  int t = kb >> 6, tb = kb & 63;
  int ks = tb >> 5, rem = tb & 31;
  int l16 = rem >> 3, bo = rem & 7;
  return ((size_t)(((r >> 4) << 3) + t) << 10) + (((l16 << 4) + (r & 15)) << 4) + (ks << 3) + bo;
}

// ---------------- prep: all packed writes COALESCED (1KB chunk per wave) ----------------
// [0,1024): convA (4 chunks/block)  [1024,2048): convB (LDS transpose + 4 chunks/block)
// [2048,2560): fproj   [2560,2592): init amin/rowsum/out
__global__ void prep_kernel(const float* __restrict__ X, unsigned char* __restrict__ A8,
                            const float* __restrict__ W, unsigned char* __restrict__ B8,
                            const float* __restrict__ feats, const float* __restrict__ proj,
                            float* __restrict__ F, unsigned long long* __restrict__ amin,
                            float* __restrict__ rowsum, float* __restrict__ out) {
  __shared__ float tile[64][65];
  const int tid = threadIdx.x;
  const int wave = tid >> 6, lane = tid & 63;
  const int l15 = lane & 15, l16 = (lane >> 4) & 3;
  int b = blockIdx.x;
  if (b < 1024) {
    // convA: chunk c = row-group g x K-tile t; lane emits its gemm fragment bytes
    const int c = b * 4 + wave;            // [0,4096)
    const int g = c >> 3, t = c & 7;
    const int r = g * 16 + l15;
    const float* base = X + (size_t)r * KDIM + t * 64 + l16 * 8;
    const float4* s0 = reinterpret_cast<const float4*>(base);        // ks=0
    const float4* s1 = reinterpret_cast<const float4*>(base + 32);   // ks=1
    float4 a0 = s0[0], a1 = s0[1], b0 = s1[0], b1 = s1[1];
    uint4 o;
    o.x = pack4_fp8(a0.x, a0.y, a0.z, a0.w);
    o.y = pack4_fp8(a1.x, a1.y, a1.z, a1.w);
    o.z = pack4_fp8(b0.x, b0.y, b0.z, b0.w);
    o.w = pack4_fp8(b1.x, b1.y, b1.z, b1.w);
    *reinterpret_cast<uint4*>(A8 + (size_t)c * 1024 + lane * 16) = o;
  } else if (b < 2048) {
    // convB: 64x64 W-tile transpose via LDS, then 4 coalesced packed chunks
    const int tb = b - 1024;
    const int bx = tb & 127, by = tb >> 7;  // bx: W-col tile, by: W-row (=K) tile
    const int c4 = tid & 15, rr = tid >> 4;
    #pragma unroll
    for (int p = 0; p < 4; ++p) {
      int row = p * 16 + rr;
      float4 v = reinterpret_cast<const float4*>(W + (size_t)(by * 64 + row) * NCOL + bx * 64)[c4];
      tile[row][c4 * 4 + 0] = v.x; tile[row][c4 * 4 + 1] = v.y;
      tile[row][c4 * 4 + 2] = v.z; tile[row][c4 * 4 + 3] = v.w;
    }
    __syncthreads();
    // wave w emits chunk for out-row-group (bx*4+w), K-tile by
    const int oc = wave * 16 + l15;        // W col within tile (= B row)
    const int kl = l16 * 8;                // W row (k) base within tile half
    float f0[8], f1[8];
    #pragma unroll
    for (int j = 0; j < 8; ++j) { f0[j] = tile[kl + j][oc]; f1[j] = tile[32 + kl + j][oc]; }
    uint4 o;
    o.x = pack4_fp8(f0[0], f0[1], f0[2], f0[3]);
    o.y = pack4_fp8(f0[4], f0[5], f0[6], f0[7]);
    o.z = pack4_fp8(f1[0], f1[1], f1[2], f1[3]);
    o.w = pack4_fp8(f1[4], f1[5], f1[6], f1[7]);
    const size_t chunk = (size_t)((bx * 4 + wave) * 8 + by);
    *reinterpret_cast<uint4*>(B8 + chunk * 1024 + lane * 16) = o;
  } else if (b < 2560) {
    b -= 2048;
    int rl = tid >> 4, d = tid & 15;
    int row = b * 16 + rl;
    const float4* fr4 = reinterpret_cast<const float4*>(feats + (size_t)row * KDIM);
    float acc = 0.f;
    #pragma unroll 4
    for (int kc = 0; kc < KDIM / 4; ++kc) {
      float4 v = fr4[kc];
      const float* p = proj + (size_t)kc * 64 + d;
      acc += v.x * p[0] + v.y * p[16] + v.z * p[32] + v.w * p[48];
    }
    F[(size_t)row * 16 + d] = acc;        // unnormalized: argmax dot == ref argmin
  } else {
    int r = (b - 2560) * 256 + tid;
    amin[r] = ~0ull;
    rowsum[r] = 0.f;
    if (b == 2560 && tid == 0) out[0] = 0.f;
  }
}

// ---------------- fused: codebook-argmax (first 512 blocks) + barrier-free reg-direct GEMM ----------------
#define TGT_BLOCKS 512
#define CB_CODES 128

__global__ __launch_bounds__(256, 3)
void gemm_targets_kernel(const unsigned char* __restrict__ A,  // packed fp8 fragments
                         const unsigned char* __restrict__ B,  // packed fp8 fragments (W^T)
                         const float* __restrict__ bias,
                         float* __restrict__ rowsum,
                         const float* __restrict__ F,
                         const float* __restrict__ cb,
                         unsigned long long* __restrict__ amin) {
  __shared__ __align__(16) float csh[CB_CODES][16];
  const int tid = threadIdx.x;
  const int bid = blockIdx.x;

  if (bid < TGT_BLOCKS) {
    // ---- targets path: block owns 1024 rows x 128 codes; u64 atomicMin merge ----
    const int r0 = (bid & 7) * 1024 + tid;
    const int c0 = (bid >> 3) * CB_CODES;
    {
      int ci = tid >> 1, half = tid & 1;
      const float4* src = reinterpret_cast<const float4*>(cb + (size_t)(c0 + ci) * 16 + half * 8);
      float4 v0 = src[0], v1 = src[1];
      float4* dst = reinterpret_cast<float4*>(&csh[ci][half * 8]);
      dst[0] = v0; dst[1] = v1;
    }
    float4 fa[4][4];
    #pragma unroll
    for (int q = 0; q < 4; ++q) {
      const float4* fp = reinterpret_cast<const float4*>(F + (size_t)(r0 + q * 256) * 16);
      fa[q][0] = fp[0]; fa[q][1] = fp[1]; fa[q][2] = fp[2]; fa[q][3] = fp[3];
    }
    __syncthreads();

    float best[4] = {3.4e38f, 3.4e38f, 3.4e38f, 3.4e38f};
    int bidx[4] = {0, 0, 0, 0};
    #pragma unroll 2
    for (int ci = 0; ci < CB_CODES; ++ci) {
      const float4* cvp = reinterpret_cast<const float4*>(&csh[ci][0]);
      float4 c0v = cvp[0], c1v = cvp[1], c2v = cvp[2], c3v = cvp[3];
      #pragma unroll
      for (int q = 0; q < 4; ++q) {
        float dot = fa[q][0].x*c0v.x + fa[q][0].y*c0v.y + fa[q][0].z*c0v.z + fa[q][0].w*c0v.w
                  + fa[q][1].x*c1v.x + fa[q][1].y*c1v.y + fa[q][1].z*c1v.z + fa[q][1].w*c1v.w
                  + fa[q][2].x*c2v.x + fa[q][2].y*c2v.y + fa[q][2].z*c2v.z + fa[q][2].w*c2v.w
                  + fa[q][3].x*c3v.x + fa[q][3].y*c3v.y + fa[q][3].z*c3v.z + fa[q][3].w*c3v.w;
        float d = -dot;
        if (d < best[q]) { best[q] = d; bidx[q] = c0 + ci; }
      }
    }
    #pragma unroll
    for (int q = 0; q < 4; ++q) {
      unsigned int u = __float_as_uint(best[q]);
      unsigned int key = (u & 0x80000000u) ? ~u : (u | 0x80000000u);  // order-preserving
      unsigned long long pk = ((unsigned long long)key << 32) | (unsigned int)bidx[q];
      atomicMin(&amin[r0 + q * 256], pk);
    }
    return;
  }

  // ---- gemm path: 128x128 tile, reg-direct fragments, NO LDS, NO barriers ----
  const int gid = bid - TGT_BLOCKS;
  const int wave = tid >> 6;
  const int lane = tid & 63;
  const int xcd = gid & 7, idx = gid >> 3;
  const int bx = xcd * 8 + (idx & 7);
  const int by = idx >> 3;
  const int row0 = by * 128;
  const int col0 = bx * 128;
  const int wr = wave >> 1, wc = wave & 1;

  f32x4 acc[4][4];
  #pragma unroll
  for (int i = 0; i < 4; ++i)
    #pragma unroll
    for (int j = 0; j < 4; ++j) acc[i][j] = (f32x4){0.f, 0.f, 0.f, 0.f};

  // fragment chunk bases: group g spans 8 K-tiles x 1KB = 8KB
  const unsigned char* abase[4];
  const unsigned char* bbase[4];
  #pragma unroll
  for (int mi = 0; mi < 4; ++mi)
    abase[mi] = A + ((size_t)((row0 >> 4) + wr * 4 + mi) << 13) + lane * 16;
  #pragma unroll
  for (int ni = 0; ni < 4; ++ni)
    bbase[ni] = B + ((size_t)((col0 >> 4) + wc * 4 + ni) << 13) + lane * 16;

  #pragma unroll
  for (int t = 0; t < 8; ++t) {
    lx2 afr[4], bfr[4];
    #pragma unroll
    for (int mi = 0; mi < 4; ++mi)
      afr[mi] = *reinterpret_cast<const lx2*>(abase[mi] + t * 1024);
    #pragma unroll
    for (int ni = 0; ni < 4; ++ni)
      bfr[ni] = *reinterpret_cast<const lx2*>(bbase[ni] + t * 1024);
    #pragma unroll
    for (int mi = 0; mi < 4; ++mi)
      #pragma unroll
      for (int ni = 0; ni < 4; ++ni) {
        acc[mi][ni] = __builtin_amdgcn_mfma_f32_16x16x32_fp8_fp8(afr[mi][0], bfr[ni][0], acc[mi][ni], 0, 0, 0);
        acc[mi][ni] = __builtin_amdgcn_mfma_f32_16x16x32_fp8_fp8(afr[mi][1], bfr[ni][1], acc[mi][ni], 0, 0, 0);
      }
  }

  // slim epilogue: per-row partial sum(exp(logit))
  const int l15 = lane & 15, l16 = lane >> 4;
  float bv[4];
  #pragma unroll
  for (int ni = 0; ni < 4; ++ni)
    bv[ni] = bias[col0 + wc * 64 + ni * 16 + l15];
  #pragma unroll
  for (int mi = 0; mi < 4; ++mi) {
    int rbase = row0 + wr * 64 + mi * 16 + l16 * 4;
    #pragma unroll
    for (int j = 0; j < 4; ++j) {
      float se = 0.f;
      #pragma unroll
      for (int ni = 0; ni < 4; ++ni)
        se += __expf(acc[mi][ni][j] + bv[ni]);
      #pragma unroll
      for (int o = 1; o < 16; o <<= 1) se += __shfl_xor(se, o);
      if (l15 == 0) atomicAdd(&rowsum[rbase + j], se);
    }
  }
}

// ---------------- merged: target logit + masked-mean loss (packed-layout gather) ----------------
// 2048 blocks x 4 waves; one row per wave; one atomicAdd per block.
__global__ void tgtloss_kernel(const unsigned char* __restrict__ A,
                               const unsigned char* __restrict__ B,
                               const float* __restrict__ bias,
                               const unsigned long long* __restrict__ amin,
                               const float* __restrict__ rowsum,
                               const int* __restrict__ lens,
                               float* __restrict__ out) {
  __shared__ float sp[4];
  const int wave = threadIdx.x >> 6, lane = threadIdx.x & 63;
  const int cnt = lens[0] + lens[1] + lens[2] + lens[3];
  const float inv = 1.0f / (float)max(cnt, 1);
  const int r = blockIdx.x * 4 + wave;
  const int tg = (int)(amin[r] & 0xffffffffull);
  // lane covers k-bytes [lane*8, lane*8+8)
  const int kb = lane << 3;
  uint2 ua = *reinterpret_cast<const uint2*>(A + pk_addr(r, kb));
  uint2 ub = *reinterpret_cast<const uint2*>(B + pk_addr(tg, kb));
  float s = 0.f;
  const unsigned char* pa = reinterpret_cast<const unsigned char*>(&ua);
  const unsigned char* pb = reinterpret_cast<const unsigned char*>(&ub);
  #pragma unroll
  for (int k = 0; k < 8; ++k) s += fp8d(pa[k]) * fp8d(pb[k]);
  #pragma unroll
  for (int o = 1; o < 64; o <<= 1) s += __shfl_xor(s, o);
  if (lane == 0) {
    const int n = r >> 11, t = r & (TSEQ - 1);
    sp[wave] = (t < lens[n]) ? (logf(rowsum[r]) - (s + bias[tg])) * inv : 0.f;
  }
  __syncthreads();
  if (threadIdx.x == 0)
    atomicAdd(out, sp[0] + sp[1] + sp[2] + sp[3]);
}

extern "C" void kernel_launch(void* const* d_in, const int* in_sizes, int n_in,
                              void* d_out, int out_size, void* d_ws, size_t ws_size,
                              hipStream_t stream) {
  const float* feats    = (const float*)d_in[0];
  const float* context  = (const float*)d_in[1];
  const int*   lens     = (const int*)d_in[2];
  const float* proj     = (const float*)d_in[3];
  const float* codebook = (const float*)d_in[4];
  const float* W_enc    = (const float*)d_in[5];
  const float* b_enc    = (const float*)d_in[6];
  float* out = (float*)d_out;

  char* ws = (char*)d_ws;
  unsigned char* A8 = (unsigned char*)(ws);                       // 4 MB (packed)
  unsigned char* B8 = (unsigned char*)(ws + 4194304);             // 4 MB (packed)
  float* F          = (float*)(ws + 8388608);                     // 512 KB
  unsigned long long* amin = (unsigned long long*)(ws + 8912896); // 64 KB
  float* rowsum     = (float*)(ws + 8978432);                     // 32 KB

  // 1) conversions (fragment-packed, coalesced chunk writes) + projection + init
  prep_kernel<<<2592, 256, 0, stream>>>(context, A8, W_enc, B8, feats, proj, F, amin, rowsum, out);
  // 2) codebook argmax (first 512 blocks)  ||  barrier-free GEMM + rowsum(exp)
  gemm_targets_kernel<<<TGT_BLOCKS + 4096, 256, 0, stream>>>(A8, B8, b_enc, rowsum, F, codebook, amin);
  // 3) target logit + masked-mean loss
  tgtloss_kernel<<<2048, 256, 0, stream>>>(A8, B8, b_enc, amin, rowsum, lens, out);
}